// Round 1
// baseline (997.557 us; speedup 1.0000x reference)
//
#include <hip/hip_runtime.h>
#include <stdint.h>

#define E 1024
#define Rk 512
#define NH 16
#define HD 64
#define BB 4
#define NT 8192
#define MT (BB * NT)  // 32768 tokens

typedef __attribute__((ext_vector_type(8))) __bf16 bf16x8;
typedef __attribute__((ext_vector_type(4))) float f32x4;
typedef __attribute__((ext_vector_type(8))) unsigned short u16x8;

typedef __attribute__((address_space(3))) void lds_void;
typedef __attribute__((address_space(1))) void g_void;

__device__ __forceinline__ unsigned short f2bf(float f) {
  uint32_t u = __float_as_uint(f);
  u += 0x7FFFu + ((u >> 16) & 1u);  // RNE
  return (unsigned short)(u >> 16);
}
__device__ __forceinline__ float bf2f(unsigned short h) {
  return __uint_as_float(((uint32_t)h) << 16);
}

// async global->LDS, 16B per lane; LDS dest is wave-uniform base + lane*16
__device__ __forceinline__ void gld16(const unsigned short* g, unsigned short* l) {
  __builtin_amdgcn_global_load_lds((g_void*)g, (lds_void*)l, 16, 0, 0);
}

// ------------------------------- fp32 -> bf16, all 7 weight matrices, 1 launch
// segs 0..5: six 512K-elem weights; segs 6,7: Wo halves. 256 blocks/seg.
__global__ __launch_bounds__(256) void cvtw_f32_bf16(
    const float* w0, const float* w1, const float* w2, const float* w3,
    const float* w4, const float* w5, const float* w6, unsigned short* o0,
    unsigned short* o1, unsigned short* o2, unsigned short* o3,
    unsigned short* o4, unsigned short* o5, unsigned short* o6) {
  const int seg = blockIdx.x >> 8;
  const size_t off = (size_t)(blockIdx.x & 255) * 256 * 8 + (size_t)threadIdx.x * 8;
  const float* s;
  unsigned short* d;
  switch (seg) {
    case 0: s = w0; d = o0; break;
    case 1: s = w1; d = o1; break;
    case 2: s = w2; d = o2; break;
    case 3: s = w3; d = o3; break;
    case 4: s = w4; d = o4; break;
    case 5: s = w5; d = o5; break;
    case 6: s = w6; d = o6; break;
    default: s = w6 + 524288; d = o6 + 524288; break;
  }
  float4 a = *(const float4*)(s + off);
  float4 b = *(const float4*)(s + off + 4);
  u16x8 r;
  r[0] = f2bf(a.x); r[1] = f2bf(a.y); r[2] = f2bf(a.z); r[3] = f2bf(a.w);
  r[4] = f2bf(b.x); r[5] = f2bf(b.y); r[6] = f2bf(b.z); r[7] = f2bf(b.w);
  *(u16x8*)(d + off) = r;
}

// ------------------------------------------------------------------- GEMM A*B^T
// C[M,N] = A[M,K] @ B[N,K]^T, bf16 in (or fp32 A when AF32=1), fp32 accum.
// EPI: 0 = store bf16; 1 = +bias, bf16; 2 = +bias, elu+1, bf16; 3 = +bias, fp32
// AF32: A operand is fp32 in global memory; converted to bf16 (RNE) while
// reg-staging into LDS (same slot global_load_lds would write: base+lane*16B).
template <int EPI, int AF32 = 0>
__global__ __launch_bounds__(256) void gemm_bt(const void* __restrict__ Av,
                                               const unsigned short* __restrict__ B,
                                               void* __restrict__ Cv,
                                               const float* __restrict__ bias,
                                               int M, int N, int K) {
  __shared__ __align__(16) unsigned short lA[128 * 32];
  __shared__ __align__(16) unsigned short lB[128 * 32];
  const int tid = threadIdx.x;
  const int wave = tid >> 6;
  const int lane = tid & 63;
  const int wm = wave >> 1, wn = wave & 1;
  const int quad = lane >> 4, l16 = lane & 15;
  const int row0 = blockIdx.x * 128;
  const int col0 = blockIdx.y * 128;
  const int srow = lane >> 2;
  const int scol = (lane & 3) * 8;

  const unsigned short* Ag = nullptr;
  const float* Agf = nullptr;
  if constexpr (AF32)
    Agf = (const float*)Av + (size_t)(row0 + wave * 32 + srow) * K + scol;
  else
    Ag = (const unsigned short*)Av + (size_t)(row0 + wave * 32 + srow) * K + scol;
  const unsigned short* Bg = B + (size_t)(col0 + wave * 32 + srow) * K + scol;
  unsigned short* lAw = &lA[wave * 1024];
  unsigned short* lBw = &lB[wave * 1024];
  const size_t rstep = (size_t)16 * K;

  f32x4 acc[4][4] = {};

  for (int kt = 0; kt < K; kt += 32) {
    float4 a0, a1, b0, b1;
    if constexpr (AF32) {
      // issue fp32 A loads before the barrier so HBM/L3 latency overlaps it
      a0 = *(const float4*)(Agf + kt);
      a1 = *(const float4*)(Agf + kt + 4);
      b0 = *(const float4*)(Agf + kt + rstep);
      b1 = *(const float4*)(Agf + kt + rstep + 4);
    }
    __syncthreads();
    if constexpr (AF32) {
      u16x8 r0, r1;
      r0[0] = f2bf(a0.x); r0[1] = f2bf(a0.y); r0[2] = f2bf(a0.z); r0[3] = f2bf(a0.w);
      r0[4] = f2bf(a1.x); r0[5] = f2bf(a1.y); r0[6] = f2bf(a1.z); r0[7] = f2bf(a1.w);
      r1[0] = f2bf(b0.x); r1[1] = f2bf(b0.y); r1[2] = f2bf(b0.z); r1[3] = f2bf(b0.w);
      r1[4] = f2bf(b1.x); r1[5] = f2bf(b1.y); r1[6] = f2bf(b1.z); r1[7] = f2bf(b1.w);
      *(u16x8*)(lAw + (size_t)lane * 8) = r0;
      *(u16x8*)(lAw + 512 + (size_t)lane * 8) = r1;
    } else {
      gld16(Ag + kt, lAw);
      gld16(Ag + kt + rstep, lAw + 512);
    }
    gld16(Bg + kt, lBw);
    gld16(Bg + kt + rstep, lBw + 512);
    __syncthreads();
    bf16x8 av[4], bv[4];
#pragma unroll
    for (int mi = 0; mi < 4; ++mi)
      av[mi] = *(const bf16x8*)&lA[(wm * 64 + mi * 16 + l16) * 32 + quad * 8];
#pragma unroll
    for (int ni = 0; ni < 4; ++ni)
      bv[ni] = *(const bf16x8*)&lB[(wn * 64 + ni * 16 + l16) * 32 + quad * 8];
#pragma unroll
    for (int mi = 0; mi < 4; ++mi)
#pragma unroll
      for (int ni = 0; ni < 4; ++ni)
        acc[mi][ni] =
            __builtin_amdgcn_mfma_f32_16x16x32_bf16(av[mi], bv[ni], acc[mi][ni], 0, 0, 0);
  }

#pragma unroll
  for (int mi = 0; mi < 4; ++mi) {
#pragma unroll
    for (int ni = 0; ni < 4; ++ni) {
#pragma unroll
      for (int r = 0; r < 4; ++r) {
        const int grow = row0 + wm * 64 + mi * 16 + quad * 4 + r;
        const int gcol = col0 + wn * 64 + ni * 16 + l16;
        float val = acc[mi][ni][r];
        if (EPI >= 1) val += bias[gcol];
        if (EPI == 2) val = (val > 0.f) ? (val + 1.f) : __expf(val);  // elu(x)+1
        if (EPI == 3)
          ((float*)Cv)[(size_t)grow * N + gcol] = val;
        else
          ((unsigned short*)Cv)[(size_t)grow * N + gcol] = f2bf(val);
      }
    }
  }
}

// ------------------------------------------------- kv^T + k_sum via MFMA
// Per (b,h): kv[d][e] = sum_n k[n][d] v[n][e]  (contraction over tokens).
// Stage 128-token tiles to LDS transposed ([d][n], [e][n], bf16 pairs packed
// as dwords), MFMA 16x16x32 with n as the K dim. Grid (64 bh, 16 n-splits),
// 512 tokens/block. Cross-wave C reduce reuses staging LDS as fp32 buffer;
// wave 0 atomicAdds to kvT[bh][e*64+d]. ksum folded into staging loads.
#define KV_ST 136  // LDS row stride (elems): 128 tokens + pad; keeps b128 16B-aligned

__global__ __launch_bounds__(256) void kv_mfma(const unsigned short* __restrict__ kq,
                                               const unsigned short* __restrict__ vq,
                                               float* __restrict__ kvT,
                                               float* __restrict__ ksum) {
  const int bh = blockIdx.x;
  const int b = bh >> 4, h = bh & 15;
  const int n0 = blockIdx.y * 512;
  __shared__ __align__(16) unsigned short sm[2 * 64 * KV_ST];  // kT | vT; reused for reduce
  unsigned short* lkT = sm;
  unsigned short* lvT = sm + 64 * KV_ST;
  __shared__ float lks[64];
  const int t = threadIdx.x;
  const int wave = t >> 6, lane = t & 63, quad = lane >> 4, l16 = lane & 15;
  const int d0 = (t & 3) * 16;  // 16 dims per thread
  const int np = t >> 2;        // token-pair 0..63 within 128-token subtile
  const size_t base = ((size_t)b * NT + n0) * E + h * HD + d0;

  if (t < 64) lks[t] = 0.f;

  f32x4 acc[4][4] = {};
  float ks[16] = {};

  for (int sub = 0; sub < 4; ++sub) {
    const size_t g = base + (size_t)(sub * 128 + 2 * np) * E;
    u16x8 ka0 = *(const u16x8*)&kq[g];
    u16x8 ka1 = *(const u16x8*)&kq[g + 8];
    u16x8 kb0 = *(const u16x8*)&kq[g + E];
    u16x8 kb1 = *(const u16x8*)&kq[g + E + 8];
    u16x8 va0 = *(const u16x8*)&vq[g];
    u16x8 va1 = *(const u16x8*)&vq[g + 8];
    u16x8 vb0 = *(const u16x8*)&vq[g + E];
    u16x8 vb1 = *(const u16x8*)&vq[g + E + 8];
    __syncthreads();  // previous iter's fragment reads complete
#pragma unroll
    for (int j = 0; j < 8; ++j) {
      *(uint32_t*)&lkT[(d0 + j) * KV_ST + 2 * np] =
          (uint32_t)ka0[j] | ((uint32_t)kb0[j] << 16);
      *(uint32_t*)&lkT[(d0 + 8 + j) * KV_ST + 2 * np] =
          (uint32_t)ka1[j] | ((uint32_t)kb1[j] << 16);
      *(uint32_t*)&lvT[(d0 + j) * KV_ST + 2 * np] =
          (uint32_t)va0[j] | ((uint32_t)vb0[j] << 16);
      *(uint32_t*)&lvT[(d0 + 8 + j) * KV_ST + 2 * np] =
          (uint32_t)va1[j] | ((uint32_t)vb1[j] << 16);
      ks[j] += bf2f(ka0[j]) + bf2f(kb0[j]);
      ks[8 + j] += bf2f(ka1[j]) + bf2f(kb1[j]);
    }
    __syncthreads();
    const int nw = wave * 32;  // each wave owns a 32-token window (split-K)
    bf16x8 af[4], bv[4];
#pragma unroll
    for (int i = 0; i < 4; ++i) {
      af[i] = *(const bf16x8*)&lkT[(i * 16 + l16) * KV_ST + nw + quad * 8];
      bv[i] = *(const bf16x8*)&lvT[(i * 16 + l16) * KV_ST + nw + quad * 8];
    }
#pragma unroll
    for (int mi = 0; mi < 4; ++mi)
#pragma unroll
      for (int ni = 0; ni < 4; ++ni)
        acc[mi][ni] =
            __builtin_amdgcn_mfma_f32_16x16x32_bf16(af[mi], bv[ni], acc[mi][ni], 0, 0, 0);
  }

  // ---- ksum: reduce over lanes sharing (lane&3) then LDS, then global
#pragma unroll
  for (int j = 0; j < 16; ++j) {
    ks[j] += __shfl_xor(ks[j], 4);
    ks[j] += __shfl_xor(ks[j], 8);
    ks[j] += __shfl_xor(ks[j], 16);
    ks[j] += __shfl_xor(ks[j], 32);
  }
  if (lane < 4) {
#pragma unroll
    for (int j = 0; j < 16; ++j) atomicAdd(&lks[(lane & 3) * 16 + j], ks[j]);
  }

  // ---- cross-wave C reduce, reusing staging LDS as fp32 (stride 66 rows)
  __syncthreads();
  float* red = (float*)sm;
  if (wave & 1) {
    float* r = red + (wave >> 1) * (64 * 66);
#pragma unroll
    for (int mi = 0; mi < 4; ++mi)
#pragma unroll
      for (int ni = 0; ni < 4; ++ni)
#pragma unroll
        for (int rr = 0; rr < 4; ++rr)
          r[(mi * 16 + quad * 4 + rr) * 66 + ni * 16 + l16] = acc[mi][ni][rr];
  }
  __syncthreads();
  if (!(wave & 1)) {
    float* r = red + (wave >> 1) * (64 * 66);
#pragma unroll
    for (int mi = 0; mi < 4; ++mi)
#pragma unroll
      for (int ni = 0; ni < 4; ++ni)
#pragma unroll
        for (int rr = 0; rr < 4; ++rr)
          acc[mi][ni][rr] += r[(mi * 16 + quad * 4 + rr) * 66 + ni * 16 + l16];
  }
  __syncthreads();
  if (wave == 2) {
#pragma unroll
    for (int mi = 0; mi < 4; ++mi)
#pragma unroll
      for (int ni = 0; ni < 4; ++ni)
#pragma unroll
        for (int rr = 0; rr < 4; ++rr)
          red[(mi * 16 + quad * 4 + rr) * 66 + ni * 16 + l16] = acc[mi][ni][rr];
  }
  __syncthreads();
  if (wave == 0) {
    float* kvb = kvT + (size_t)bh * 4096;
#pragma unroll
    for (int mi = 0; mi < 4; ++mi)
#pragma unroll
      for (int ni = 0; ni < 4; ++ni)
#pragma unroll
        for (int rr = 0; rr < 4; ++rr) {
          const int d = mi * 16 + quad * 4 + rr;
          const int e = ni * 16 + l16;
          atomicAdd(&kvb[e * 64 + d], acc[mi][ni][rr] + red[d * 66 + e]);
        }
  }
  if (t < 64) atomicAdd(&ksum[bh * 64 + t], lks[t]);
}

// ----------------------------------------------- apply: ctx = (q @ kv) / denom
__global__ __launch_bounds__(256) void attn_apply(const unsigned short* __restrict__ q,
                                                  const float* __restrict__ kvT,
                                                  const float* __restrict__ ksum,
                                                  unsigned short* __restrict__ ctx) {
  const int bh = blockIdx.x;
  const int b = bh >> 4, h = bh & 15;
  const int n0 = blockIdx.y * 64;
  __shared__ __align__(16) unsigned short lq[64 * 64];   // [tok][d] bf16
  __shared__ __align__(16) unsigned short lkv[64 * 64];  // [e][d]  bf16
  __shared__ float lks[64];
  __shared__ float lden[64];
  __shared__ float part[64][4];
  const int t = threadIdx.x;
  const size_t qbase = ((size_t)b * NT + n0) * E + h * HD;

  {
    const int i = t >> 2, p = t & 3;
    *(u16x8*)&lq[i * 64 + p * 16] = *(const u16x8*)&q[qbase + (size_t)i * E + p * 16];
    *(u16x8*)&lq[i * 64 + p * 16 + 8] =
        *(const u16x8*)&q[qbase + (size_t)i * E + p * 16 + 8];
    const int e = i, dd0 = p * 16;
    const float* src = kvT + (size_t)bh * 4096 + e * 64 + dd0;
#pragma unroll
    for (int j = 0; j < 16; j += 4) {
      float4 f = *(const float4*)(src + j);
      lkv[e * 64 + dd0 + j + 0] = f2bf(f.x);
      lkv[e * 64 + dd0 + j + 1] = f2bf(f.y);
      lkv[e * 64 + dd0 + j + 2] = f2bf(f.z);
      lkv[e * 64 + dd0 + j + 3] = f2bf(f.w);
    }
    if (t < 64) lks[t] = ksum[bh * 64 + t];
  }
  __syncthreads();
  {
    const int i = t >> 2, p = (t & 3) * 16;
    float s = 0.f;
#pragma unroll
    for (int d = 0; d < 16; ++d) s += bf2f(lq[i * 64 + p + d]) * lks[p + d];
    part[i][t & 3] = s;
  }
  __syncthreads();
  if (t < 64) lden[t] = part[t][0] + part[t][1] + part[t][2] + part[t][3] + 1e-6f;
  __syncthreads();

  const int wave = t >> 6, lane = t & 63, quad = lane >> 4, l16 = lane & 15;
  const int m0 = wave * 16;
  f32x4 acc[4] = {};
#pragma unroll
  for (int kk = 0; kk < 2; ++kk) {
    bf16x8 af = *(const bf16x8*)&lq[(m0 + l16) * 64 + kk * 32 + quad * 8];
#pragma unroll
    for (int ni = 0; ni < 4; ++ni) {
      bf16x8 bv = *(const bf16x8*)&lkv[(ni * 16 + l16) * 64 + kk * 32 + quad * 8];
      acc[ni] = __builtin_amdgcn_mfma_f32_16x16x32_bf16(af, bv, acc[ni], 0, 0, 0);
    }
  }
#pragma unroll
  for (int ni = 0; ni < 4; ++ni) {
#pragma unroll
    for (int r = 0; r < 4; ++r) {
      const int m = m0 + quad * 4 + r;
      const float val = acc[ni][r] / lden[m];
      ctx[qbase + (size_t)m * E + ni * 16 + l16] = f2bf(val);
    }
  }
}

// -----------------------------------------------------------------------------
extern "C" void kernel_launch(void* const* d_in, const int* in_sizes, int n_in,
                              void* d_out, int out_size, void* d_ws, size_t ws_size,
                              hipStream_t stream) {
  (void)in_sizes; (void)n_in; (void)out_size; (void)ws_size;
  const float* query = (const float*)d_in[0];
  const float* key_ = (const float*)d_in[1];
  const float* value = (const float*)d_in[2];
  const float* Wqd = (const float*)d_in[3];
  const float* Wqu = (const float*)d_in[4];
  const float* bqu = (const float*)d_in[5];
  const float* Wkd = (const float*)d_in[6];
  const float* Wku = (const float*)d_in[7];
  const float* bku = (const float*)d_in[8];
  const float* Wvd = (const float*)d_in[9];
  const float* Wvu = (const float*)d_in[10];
  const float* bvu = (const float*)d_in[11];
  const float* Wo = (const float*)d_in[12];
  const float* bo = (const float*)d_in[13];
  float* out = (float*)d_out;

  // workspace carve (≈233 MB)
  char* w = (char*)d_ws;
  unsigned short* qb = (unsigned short*)w; w += (size_t)MT * E * 2;
  unsigned short* kb = (unsigned short*)w; w += (size_t)MT * E * 2;
  unsigned short* vb = (unsigned short*)w; w += (size_t)MT * E * 2;
  unsigned short* tb = (unsigned short*)w; w += (size_t)MT * Rk * 2;
  unsigned short* wqd = (unsigned short*)w; w += (size_t)Rk * E * 2;
  unsigned short* wqu = (unsigned short*)w; w += (size_t)E * Rk * 2;
  unsigned short* wkd = (unsigned short*)w; w += (size_t)Rk * E * 2;
  unsigned short* wku = (unsigned short*)w; w += (size_t)E * Rk * 2;
  unsigned short* wvd = (unsigned short*)w; w += (size_t)Rk * E * 2;
  unsigned short* wvu = (unsigned short*)w; w += (size_t)E * Rk * 2;
  unsigned short* wo = (unsigned short*)w; w += (size_t)E * E * 2;
  float* kvT = (float*)w; w += (size_t)64 * 4096 * 4;
  float* ksg = (float*)w; w += (size_t)64 * 64 * 4;

  // weights convert only; q/k/v fp32->bf16 is fused into the down-proj GEMMs
  cvtw_f32_bf16<<<2048, 256, 0, stream>>>(Wqd, Wqu, Wkd, Wku, Wvd, Wvu, Wo,
                                          wqd, wqu, wkd, wku, wvd, wvu, wo);

  dim3 blk(256);
  // down-proj: fp32 A consumed directly (fused convert), bf16 weights
  gemm_bt<0, 1><<<dim3(MT / 128, Rk / 128), blk, 0, stream>>>(query, wqd, tb, nullptr, MT, Rk, E);
  gemm_bt<2><<<dim3(MT / 128, E / 128), blk, 0, stream>>>(tb, wqu, qb, bqu, MT, E, Rk);
  gemm_bt<0, 1><<<dim3(MT / 128, Rk / 128), blk, 0, stream>>>(key_, wkd, tb, nullptr, MT, Rk, E);
  gemm_bt<2><<<dim3(MT / 128, E / 128), blk, 0, stream>>>(tb, wku, kb, bku, MT, E, Rk);
  gemm_bt<0, 1><<<dim3(MT / 128, Rk / 128), blk, 0, stream>>>(value, wvd, tb, nullptr, MT, Rk, E);
  gemm_bt<1><<<dim3(MT / 128, E / 128), blk, 0, stream>>>(tb, wvu, vb, bvu, MT, E, Rk);

  // attention core
  hipMemsetAsync(kvT, 0, (size_t)(64 * 4096 + 64 * 64) * sizeof(float), stream);
  kv_mfma<<<dim3(64, 16), blk, 0, stream>>>(kb, vb, kvT, ksg);
  attn_apply<<<dim3(64, 128), blk, 0, stream>>>(qb, kvT, ksg, qb);

  // output projection -> fp32 d_out
  gemm_bt<3><<<dim3(MT / 128, E / 128), blk, 0, stream>>>(qb, wo, out, bo, MT, E, E);
}

// Round 2
// 874.440 us; speedup vs baseline: 1.1408x; 1.1408x over previous
//
#include <hip/hip_runtime.h>
#include <stdint.h>

#define E 1024
#define Rk 512
#define NH 16
#define HD 64
#define BB 4
#define NT 8192
#define MT (BB * NT)  // 32768 tokens

typedef __attribute__((ext_vector_type(8))) __bf16 bf16x8;
typedef __attribute__((ext_vector_type(4))) float f32x4;
typedef __attribute__((ext_vector_type(8))) unsigned short u16x8;

typedef __attribute__((address_space(3))) void lds_void;
typedef __attribute__((address_space(1))) void g_void;

__device__ __forceinline__ unsigned short f2bf(float f) {
  uint32_t u = __float_as_uint(f);
  u += 0x7FFFu + ((u >> 16) & 1u);  // RNE
  return (unsigned short)(u >> 16);
}
__device__ __forceinline__ float bf2f(unsigned short h) {
  return __uint_as_float(((uint32_t)h) << 16);
}

// async global->LDS, 16B per lane; LDS dest is wave-uniform base + lane*16
__device__ __forceinline__ void gld16(const unsigned short* g, unsigned short* l) {
  __builtin_amdgcn_global_load_lds((g_void*)g, (lds_void*)l, 16, 0, 0);
}

// ------------------------------------------- fp32 -> bf16 (3 equal tensors)
__global__ __launch_bounds__(256) void cvt3_f32_bf16(
    const float* __restrict__ s0, const float* __restrict__ s1,
    const float* __restrict__ s2, unsigned short* __restrict__ d0,
    unsigned short* __restrict__ d1, unsigned short* __restrict__ d2) {
  const float* s = (blockIdx.y == 0) ? s0 : (blockIdx.y == 1) ? s1 : s2;
  unsigned short* d = (blockIdx.y == 0) ? d0 : (blockIdx.y == 1) ? d1 : d2;
  const size_t i = ((size_t)blockIdx.x * 256 + threadIdx.x) * 8;
  float4 a = *(const float4*)(s + i);
  float4 b = *(const float4*)(s + i + 4);
  u16x8 r;
  r[0] = f2bf(a.x); r[1] = f2bf(a.y); r[2] = f2bf(a.z); r[3] = f2bf(a.w);
  r[4] = f2bf(b.x); r[5] = f2bf(b.y); r[6] = f2bf(b.z); r[7] = f2bf(b.w);
  *(u16x8*)(d + i) = r;
}

// ------------------------------- fp32 -> bf16, all 7 weight matrices, 1 launch
__global__ __launch_bounds__(256) void cvtw_f32_bf16(
    const float* w0, const float* w1, const float* w2, const float* w3,
    const float* w4, const float* w5, const float* w6, unsigned short* o0,
    unsigned short* o1, unsigned short* o2, unsigned short* o3,
    unsigned short* o4, unsigned short* o5, unsigned short* o6) {
  const int seg = blockIdx.x >> 8;
  const size_t off = (size_t)(blockIdx.x & 255) * 256 * 8 + (size_t)threadIdx.x * 8;
  const float* s;
  unsigned short* d;
  switch (seg) {
    case 0: s = w0; d = o0; break;
    case 1: s = w1; d = o1; break;
    case 2: s = w2; d = o2; break;
    case 3: s = w3; d = o3; break;
    case 4: s = w4; d = o4; break;
    case 5: s = w5; d = o5; break;
    case 6: s = w6; d = o6; break;
    default: s = w6 + 524288; d = o6 + 524288; break;
  }
  float4 a = *(const float4*)(s + off);
  float4 b = *(const float4*)(s + off + 4);
  u16x8 r;
  r[0] = f2bf(a.x); r[1] = f2bf(a.y); r[2] = f2bf(a.z); r[3] = f2bf(a.w);
  r[4] = f2bf(b.x); r[5] = f2bf(b.y); r[6] = f2bf(b.z); r[7] = f2bf(b.w);
  *(u16x8*)(d + off) = r;
}

// ------------------------------------------------------------- GEMM A*B^T 256²
// C[M,N] = A[M,K] @ B[N,K]^T, bf16 in, fp32 accum.
// 256x256 tile, BK=64, 8 waves (2M x 4N), 512 threads, 128 KiB LDS double-buf.
// Counted vmcnt(8) + raw s_barrier (no drain-to-0); XOR-swizzled LDS slots
// (physical 16B slot p of row r holds global slot p^(r&7); pre-swizzled global
// source keeps global_load_lds dest linear — rule 21 both-sides).
// EPI: 0 = store bf16; 1 = +bias, bf16; 2 = +bias, elu+1, bf16; 3 = +bias, fp32
template <int EPI>
__global__ __launch_bounds__(512, 2) void gemm256(const unsigned short* __restrict__ A,
                                                  const unsigned short* __restrict__ B,
                                                  void* __restrict__ Cv,
                                                  const float* __restrict__ bias,
                                                  int M, int N, int K) {
  __shared__ __align__(16) unsigned short lds[2][2][256 * 64];  // [buf][A|B][row*64+col]
  const int tid = threadIdx.x;
  const int wave = tid >> 6;
  const int lane = tid & 63;
  const int wm = wave >> 2, wn = wave & 3;   // 2M x 4N wave grid
  const int quad = lane >> 4, l16 = lane & 15;

  // XCD-aware bijective swizzle, x-major linearization (A-panel L2 reuse).
  // nwg = 256 or 512 here -> nwg % 8 == 0.
  const int gy = gridDim.y;
  const int nwg = gridDim.x * gy;
  int bid = blockIdx.x * gy + blockIdx.y;
  bid = (bid & 7) * (nwg >> 3) + (bid >> 3);
  const int row0 = (bid / gy) * 256;
  const int col0 = (bid % gy) * 256;

  // staging role: row-in-chunk = wave*8 + (lane>>3); 16B slot = lane&7,
  // pre-swizzled source column slot = (lane&7) ^ (row&7) = (lane&7)^(lane>>3)
  const int srowi = lane >> 3;
  const int cs = ((lane & 7) ^ srowi) * 8;  // element offset of this lane's 16B
  const int wr8 = wave * 8 + srowi;         // 0..63 within each 64-row chunk
  const unsigned short* Ab = A + (size_t)(row0 + wr8) * K + cs;
  const unsigned short* Bb = B + (size_t)(col0 + wr8) * K + cs;
  const int lbase = wave * 8 * 64;  // wave-uniform LDS elem offset within chunk

  const int NTK = K >> 6;  // K-tiles of 64

  auto STAGE = [&](int tk, int bb) {
    const size_t ko = (size_t)tk * 64;
    unsigned short* la = &lds[bb][0][lbase];
    unsigned short* lb = &lds[bb][1][lbase];
#pragma unroll
    for (int j = 0; j < 4; ++j)
      gld16(Ab + ko + (size_t)j * 64 * K, la + j * 4096);
#pragma unroll
    for (int j = 0; j < 4; ++j)
      gld16(Bb + ko + (size_t)j * 64 * K, lb + j * 4096);
  };

  f32x4 acc[8][4] = {};

  STAGE(0, 0);
  if (NTK > 1) STAGE(1, 1);

  const int sA = l16 & 7;  // read-side swizzle key (row&7 == l16&7 for frag rows)

  for (int t = 0; t < NTK; ++t) {
    const int c = t & 1;
    // tile t landed when only tile t+1's 8 loads remain outstanding
    if (t + 1 < NTK)
      asm volatile("s_waitcnt vmcnt(8)" ::: "memory");
    else
      asm volatile("s_waitcnt vmcnt(0)" ::: "memory");
    __builtin_amdgcn_sched_barrier(0);
    __builtin_amdgcn_s_barrier();
    __builtin_amdgcn_sched_barrier(0);

    const unsigned short* lA = &lds[c][0][0];
    const unsigned short* lB = &lds[c][1][0];
#pragma unroll
    for (int kk = 0; kk < 2; ++kk) {
      const int so = ((kk * 4 + quad) ^ sA) * 8;  // swizzled 16B slot (elems)
      bf16x8 af[8], bf[4];
#pragma unroll
      for (int mi = 0; mi < 8; ++mi)
        af[mi] = *(const bf16x8*)&lA[(wm * 128 + mi * 16 + l16) * 64 + so];
#pragma unroll
      for (int ni = 0; ni < 4; ++ni)
        bf[ni] = *(const bf16x8*)&lB[(wn * 64 + ni * 16 + l16) * 64 + so];
      __builtin_amdgcn_s_setprio(1);
#pragma unroll
      for (int mi = 0; mi < 8; ++mi)
#pragma unroll
        for (int ni = 0; ni < 4; ++ni)
          acc[mi][ni] =
              __builtin_amdgcn_mfma_f32_16x16x32_bf16(af[mi], bf[ni], acc[mi][ni], 0, 0, 0);
      __builtin_amdgcn_s_setprio(0);
    }
    asm volatile("s_waitcnt lgkmcnt(0)" ::: "memory");
    __builtin_amdgcn_sched_barrier(0);
    __builtin_amdgcn_s_barrier();
    __builtin_amdgcn_sched_barrier(0);
    if (t + 2 < NTK) STAGE(t + 2, c);  // buf c fully consumed; refill
  }

  // epilogue
  float bias_v[4];
  if (EPI >= 1) {
#pragma unroll
    for (int ni = 0; ni < 4; ++ni) bias_v[ni] = bias[col0 + wn * 64 + ni * 16 + l16];
  }
#pragma unroll
  for (int mi = 0; mi < 8; ++mi) {
#pragma unroll
    for (int ni = 0; ni < 4; ++ni) {
#pragma unroll
      for (int r = 0; r < 4; ++r) {
        const int grow = row0 + wm * 128 + mi * 16 + quad * 4 + r;
        const int gcol = col0 + wn * 64 + ni * 16 + l16;
        float val = acc[mi][ni][r];
        if (EPI >= 1) val += bias_v[ni];
        if (EPI == 2) val = (val > 0.f) ? (val + 1.f) : __expf(val);  // elu(x)+1
        if (EPI == 3)
          ((float*)Cv)[(size_t)grow * N + gcol] = val;
        else
          ((unsigned short*)Cv)[(size_t)grow * N + gcol] = f2bf(val);
      }
    }
  }
}

// ------------------------------------------------- kv^T + k_sum via MFMA
#define KV_ST 136  // LDS row stride (elems): 128 tokens + pad; keeps b128 16B-aligned

__global__ __launch_bounds__(256) void kv_mfma(const unsigned short* __restrict__ kq,
                                               const unsigned short* __restrict__ vq,
                                               float* __restrict__ kvT,
                                               float* __restrict__ ksum) {
  const int bh = blockIdx.x;
  const int b = bh >> 4, h = bh & 15;
  const int n0 = blockIdx.y * 512;
  __shared__ __align__(16) unsigned short sm[2 * 64 * KV_ST];  // kT | vT; reused for reduce
  unsigned short* lkT = sm;
  unsigned short* lvT = sm + 64 * KV_ST;
  __shared__ float lks[64];
  const int t = threadIdx.x;
  const int wave = t >> 6, lane = t & 63, quad = lane >> 4, l16 = lane & 15;
  const int d0 = (t & 3) * 16;  // 16 dims per thread
  const int np = t >> 2;        // token-pair 0..63 within 128-token subtile
  const size_t base = ((size_t)b * NT + n0) * E + h * HD + d0;

  if (t < 64) lks[t] = 0.f;

  f32x4 acc[4][4] = {};
  float ks[16] = {};

  for (int sub = 0; sub < 4; ++sub) {
    const size_t g = base + (size_t)(sub * 128 + 2 * np) * E;
    u16x8 ka0 = *(const u16x8*)&kq[g];
    u16x8 ka1 = *(const u16x8*)&kq[g + 8];
    u16x8 kb0 = *(const u16x8*)&kq[g + E];
    u16x8 kb1 = *(const u16x8*)&kq[g + E + 8];
    u16x8 va0 = *(const u16x8*)&vq[g];
    u16x8 va1 = *(const u16x8*)&vq[g + 8];
    u16x8 vb0 = *(const u16x8*)&vq[g + E];
    u16x8 vb1 = *(const u16x8*)&vq[g + E + 8];
    __syncthreads();  // previous iter's fragment reads complete
#pragma unroll
    for (int j = 0; j < 8; ++j) {
      *(uint32_t*)&lkT[(d0 + j) * KV_ST + 2 * np] =
          (uint32_t)ka0[j] | ((uint32_t)kb0[j] << 16);
      *(uint32_t*)&lkT[(d0 + 8 + j) * KV_ST + 2 * np] =
          (uint32_t)ka1[j] | ((uint32_t)kb1[j] << 16);
      *(uint32_t*)&lvT[(d0 + j) * KV_ST + 2 * np] =
          (uint32_t)va0[j] | ((uint32_t)vb0[j] << 16);
      *(uint32_t*)&lvT[(d0 + 8 + j) * KV_ST + 2 * np] =
          (uint32_t)va1[j] | ((uint32_t)vb1[j] << 16);
      ks[j] += bf2f(ka0[j]) + bf2f(kb0[j]);
      ks[8 + j] += bf2f(ka1[j]) + bf2f(kb1[j]);
    }
    __syncthreads();
    const int nw = wave * 32;  // each wave owns a 32-token window (split-K)
    bf16x8 af[4], bv[4];
#pragma unroll
    for (int i = 0; i < 4; ++i) {
      af[i] = *(const bf16x8*)&lkT[(i * 16 + l16) * KV_ST + nw + quad * 8];
      bv[i] = *(const bf16x8*)&lvT[(i * 16 + l16) * KV_ST + nw + quad * 8];
    }
#pragma unroll
    for (int mi = 0; mi < 4; ++mi)
#pragma unroll
      for (int ni = 0; ni < 4; ++ni)
        acc[mi][ni] =
            __builtin_amdgcn_mfma_f32_16x16x32_bf16(af[mi], bv[ni], acc[mi][ni], 0, 0, 0);
  }

  // ---- ksum: reduce over lanes sharing (lane&3) then LDS, then global
#pragma unroll
  for (int j = 0; j < 16; ++j) {
    ks[j] += __shfl_xor(ks[j], 4);
    ks[j] += __shfl_xor(ks[j], 8);
    ks[j] += __shfl_xor(ks[j], 16);
    ks[j] += __shfl_xor(ks[j], 32);
  }
  if (lane < 4) {
#pragma unroll
    for (int j = 0; j < 16; ++j) atomicAdd(&lks[(lane & 3) * 16 + j], ks[j]);
  }

  // ---- cross-wave C reduce, reusing staging LDS as fp32 (stride 66 rows)
  __syncthreads();
  float* red = (float*)sm;
  if (wave & 1) {
    float* r = red + (wave >> 1) * (64 * 66);
#pragma unroll
    for (int mi = 0; mi < 4; ++mi)
#pragma unroll
      for (int ni = 0; ni < 4; ++ni)
#pragma unroll
        for (int rr = 0; rr < 4; ++rr)
          r[(mi * 16 + quad * 4 + rr) * 66 + ni * 16 + l16] = acc[mi][ni][rr];
  }
  __syncthreads();
  if (!(wave & 1)) {
    float* r = red + (wave >> 1) * (64 * 66);
#pragma unroll
    for (int mi = 0; mi < 4; ++mi)
#pragma unroll
      for (int ni = 0; ni < 4; ++ni)
#pragma unroll
        for (int rr = 0; rr < 4; ++rr)
          acc[mi][ni][rr] += r[(mi * 16 + quad * 4 + rr) * 66 + ni * 16 + l16];
  }
  __syncthreads();
  if (wave == 2) {
#pragma unroll
    for (int mi = 0; mi < 4; ++mi)
#pragma unroll
      for (int ni = 0; ni < 4; ++ni)
#pragma unroll
        for (int rr = 0; rr < 4; ++rr)
          red[(mi * 16 + quad * 4 + rr) * 66 + ni * 16 + l16] = acc[mi][ni][rr];
  }
  __syncthreads();
  if (wave == 0) {
    float* kvb = kvT + (size_t)bh * 4096;
#pragma unroll
    for (int mi = 0; mi < 4; ++mi)
#pragma unroll
      for (int ni = 0; ni < 4; ++ni)
#pragma unroll
        for (int rr = 0; rr < 4; ++rr) {
          const int d = mi * 16 + quad * 4 + rr;
          const int e = ni * 16 + l16;
          atomicAdd(&kvb[e * 64 + d], acc[mi][ni][rr] + red[d * 66 + e]);
        }
  }
  if (t < 64) atomicAdd(&ksum[bh * 64 + t], lks[t]);
}

// ----------------------------------------------- apply: ctx = (q @ kv) / denom
__global__ __launch_bounds__(256) void attn_apply(const unsigned short* __restrict__ q,
                                                  const float* __restrict__ kvT,
                                                  const float* __restrict__ ksum,
                                                  unsigned short* __restrict__ ctx) {
  const int bh = blockIdx.x;
  const int b = bh >> 4, h = bh & 15;
  const int n0 = blockIdx.y * 64;
  __shared__ __align__(16) unsigned short lq[64 * 64];   // [tok][d] bf16
  __shared__ __align__(16) unsigned short lkv[64 * 64];  // [e][d]  bf16
  __shared__ float lks[64];
  __shared__ float lden[64];
  __shared__ float part[64][4];
  const int t = threadIdx.x;
  const size_t qbase = ((size_t)b * NT + n0) * E + h * HD;

  {
    const int i = t >> 2, p = t & 3;
    *(u16x8*)&lq[i * 64 + p * 16] = *(const u16x8*)&q[qbase + (size_t)i * E + p * 16];
    *(u16x8*)&lq[i * 64 + p * 16 + 8] =
        *(const u16x8*)&q[qbase + (size_t)i * E + p * 16 + 8];
    const int e = i, dd0 = p * 16;
    const float* src = kvT + (size_t)bh * 4096 + e * 64 + dd0;
#pragma unroll
    for (int j = 0; j < 16; j += 4) {
      float4 f = *(const float4*)(src + j);
      lkv[e * 64 + dd0 + j + 0] = f2bf(f.x);
      lkv[e * 64 + dd0 + j + 1] = f2bf(f.y);
      lkv[e * 64 + dd0 + j + 2] = f2bf(f.z);
      lkv[e * 64 + dd0 + j + 3] = f2bf(f.w);
    }
    if (t < 64) lks[t] = ksum[bh * 64 + t];
  }
  __syncthreads();
  {
    const int i = t >> 2, p = (t & 3) * 16;
    float s = 0.f;
#pragma unroll
    for (int d = 0; d < 16; ++d) s += bf2f(lq[i * 64 + p + d]) * lks[p + d];
    part[i][t & 3] = s;
  }
  __syncthreads();
  if (t < 64) lden[t] = part[t][0] + part[t][1] + part[t][2] + part[t][3] + 1e-6f;
  __syncthreads();

  const int wave = t >> 6, lane = t & 63, quad = lane >> 4, l16 = lane & 15;
  const int m0 = wave * 16;
  f32x4 acc[4] = {};
#pragma unroll
  for (int kk = 0; kk < 2; ++kk) {
    bf16x8 af = *(const bf16x8*)&lq[(m0 + l16) * 64 + kk * 32 + quad * 8];
#pragma unroll
    for (int ni = 0; ni < 4; ++ni) {
      bf16x8 bv = *(const bf16x8*)&lkv[(ni * 16 + l16) * 64 + kk * 32 + quad * 8];
      acc[ni] = __builtin_amdgcn_mfma_f32_16x16x32_bf16(af, bv, acc[ni], 0, 0, 0);
    }
  }
#pragma unroll
  for (int ni = 0; ni < 4; ++ni) {
#pragma unroll
    for (int r = 0; r < 4; ++r) {
      const int m = m0 + quad * 4 + r;
      const float val = acc[ni][r] / lden[m];
      ctx[qbase + (size_t)m * E + ni * 16 + l16] = f2bf(val);
    }
  }
}

// -----------------------------------------------------------------------------
extern "C" void kernel_launch(void* const* d_in, const int* in_sizes, int n_in,
                              void* d_out, int out_size, void* d_ws, size_t ws_size,
                              hipStream_t stream) {
  (void)in_sizes; (void)n_in; (void)out_size; (void)ws_size;
  const float* query = (const float*)d_in[0];
  const float* key_ = (const float*)d_in[1];
  const float* value = (const float*)d_in[2];
  const float* Wqd = (const float*)d_in[3];
  const float* Wqu = (const float*)d_in[4];
  const float* bqu = (const float*)d_in[5];
  const float* Wkd = (const float*)d_in[6];
  const float* Wku = (const float*)d_in[7];
  const float* bku = (const float*)d_in[8];
  const float* Wvd = (const float*)d_in[9];
  const float* Wvu = (const float*)d_in[10];
  const float* bvu = (const float*)d_in[11];
  const float* Wo = (const float*)d_in[12];
  const float* bo = (const float*)d_in[13];
  float* out = (float*)d_out;

  // workspace carve (≈233 MB)
  char* w = (char*)d_ws;
  unsigned short* qb = (unsigned short*)w; w += (size_t)MT * E * 2;
  unsigned short* kb = (unsigned short*)w; w += (size_t)MT * E * 2;
  unsigned short* vb = (unsigned short*)w; w += (size_t)MT * E * 2;
  unsigned short* tb = (unsigned short*)w; w += (size_t)MT * Rk * 2;
  unsigned short* wqd = (unsigned short*)w; w += (size_t)Rk * E * 2;
  unsigned short* wqu = (unsigned short*)w; w += (size_t)E * Rk * 2;
  unsigned short* wkd = (unsigned short*)w; w += (size_t)Rk * E * 2;
  unsigned short* wku = (unsigned short*)w; w += (size_t)E * Rk * 2;
  unsigned short* wvd = (unsigned short*)w; w += (size_t)Rk * E * 2;
  unsigned short* wvu = (unsigned short*)w; w += (size_t)E * Rk * 2;
  unsigned short* wo = (unsigned short*)w; w += (size_t)E * E * 2;
  float* kvT = (float*)w; w += (size_t)64 * 4096 * 4;
  float* ksg = (float*)w; w += (size_t)64 * 64 * 4;

  // converts: 2 launches total
  cvt3_f32_bf16<<<dim3(MT * E / 2048, 3), 256, 0, stream>>>(query, key_, value, qb, kb, vb);
  cvtw_f32_bf16<<<2048, 256, 0, stream>>>(Wqd, Wqu, Wkd, Wku, Wvd, Wvu, Wo,
                                          wqd, wqu, wkd, wku, wvd, wvu, wo);

  dim3 blk(512);
  gemm256<0><<<dim3(MT / 256, Rk / 256), blk, 0, stream>>>(qb, wqd, tb, nullptr, MT, Rk, E);
  gemm256<2><<<dim3(MT / 256, E / 256), blk, 0, stream>>>(tb, wqu, qb, bqu, MT, E, Rk);
  gemm256<0><<<dim3(MT / 256, Rk / 256), blk, 0, stream>>>(kb, wkd, tb, nullptr, MT, Rk, E);
  gemm256<2><<<dim3(MT / 256, E / 256), blk, 0, stream>>>(tb, wku, kb, bku, MT, E, Rk);
  gemm256<0><<<dim3(MT / 256, Rk / 256), blk, 0, stream>>>(vb, wvd, tb, nullptr, MT, Rk, E);
  gemm256<1><<<dim3(MT / 256, E / 256), blk, 0, stream>>>(tb, wvu, vb, bvu, MT, E, Rk);

  // attention core
  hipMemsetAsync(kvT, 0, (size_t)(64 * 4096 + 64 * 64) * sizeof(float), stream);
  kv_mfma<<<dim3(64, 16), dim3(256), 0, stream>>>(kb, vb, kvT, ksg);
  attn_apply<<<dim3(64, 128), dim3(256), 0, stream>>>(qb, kvT, ksg, qb);

  // output projection -> fp32 d_out
  gemm256<3><<<dim3(MT / 256, E / 256), blk, 0, stream>>>(qb, wo, out, bo, MT, E, E);
}